// Round 1
// baseline (523.475 us; speedup 1.0000x reference)
//
#include <hip/hip_runtime.h>
#include <hip/hip_bf16.h>
#include <hip/hip_fp16.h>

typedef _Float16 half8 __attribute__((ext_vector_type(8)));
typedef float floatx4 __attribute__((ext_vector_type(4)));

#define HID 128
#define TILE_M 32
#define LDA 136   // padded fp16 row stride (272 B): uniform bank spread for ds_read_b128

// ---------------------------------------------------------------------------
// Kernel 1: node_emb[n][c] = x[n]@Wa + ba + pos[n]@Wp + bp   -> fp16
// ---------------------------------------------------------------------------
__global__ __launch_bounds__(256) void node_emb_kernel(
    const float* __restrict__ x, const float* __restrict__ pos,
    const float* __restrict__ Wa, const float* __restrict__ ba,
    const float* __restrict__ Wp, const float* __restrict__ bp,
    _Float16* __restrict__ nodeEmb, int N)
{
    __shared__ float sWa[16 * HID];
    __shared__ float sWp[3 * HID];
    __shared__ float sb[HID];
    for (int i = threadIdx.x; i < 16 * HID; i += 256) sWa[i] = Wa[i];
    for (int i = threadIdx.x; i < 3 * HID;  i += 256) sWp[i] = Wp[i];
    for (int i = threadIdx.x; i < HID;      i += 256) sb[i] = ba[i] + bp[i];
    __syncthreads();

    long long total = (long long)N * HID;
    for (long long idx = (long long)blockIdx.x * 256 + threadIdx.x; idx < total;
         idx += (long long)gridDim.x * 256) {
        int n = (int)(idx >> 7);
        int c = (int)(idx & (HID - 1));
        const float* xr = x + (size_t)n * 16;
        const float* pr = pos + (size_t)n * 3;
        float s = sb[c];
        #pragma unroll
        for (int k = 0; k < 16; ++k) s += xr[k] * sWa[k * HID + c];
        #pragma unroll
        for (int k = 0; k < 3; ++k)  s += pr[k] * sWp[k * HID + c];
        nodeEmb[idx] = (_Float16)s;
    }
}

// ---------------------------------------------------------------------------
// Kernel 2: per-edge MLP. Persistent blocks, 4 waves, 32 edges per tile.
//   layer1: [32x256]@[256x128] via src@W1a + dst@W1b + dist*w1c + b1, silu
//   layer2: [32x128]@[128x128] + b2, silu
//   layer3: [32x128]@[128x4]   + b3 (VALU)
// Weight MFMA fragments held in registers for the whole block lifetime.
// ---------------------------------------------------------------------------
__global__ __launch_bounds__(256, 3) void edge_mlp_kernel(
    const _Float16* __restrict__ nodeEmb,
    const float* __restrict__ pos,
    const int* __restrict__ eidx,          // [2][E]
    const float* __restrict__ W1, const float* __restrict__ b1,   // [257][128]
    const float* __restrict__ W2, const float* __restrict__ b2,   // [128][128]
    const float* __restrict__ W3, const float* __restrict__ b3,   // [128][4]
    float* __restrict__ out, int E, int nTiles)
{
    __shared__ __align__(16) _Float16 sA[2][TILE_M][LDA]; // src/dst gathered rows
    __shared__ __align__(16) _Float16 sH[TILE_M][LDA];    // H1 then H2
    __shared__ float sW3[HID * 4];
    __shared__ float sB3[4];
    __shared__ float sDist[TILE_M];

    const int t    = threadIdx.x;
    const int wave = t >> 6;
    const int lane = t & 63;
    const int quad = lane >> 4;
    const int l16  = lane & 15;
    const int colbase = wave * 32;        // each wave owns 32 output columns

    for (int i = t; i < HID * 4; i += 256) sW3[i] = W3[i];
    if (t < 4) sB3[t] = b3[t];

    // ---- preload weight B-fragments: elem j -> W[k0 + quad*8 + j][col] ----
    half8 w1f[8][2];
    half8 w2f[4][2];
    float w1c[2], b1f[2], b2f[2];
    #pragma unroll
    for (int ct = 0; ct < 2; ++ct) {
        int col = colbase + ct * 16 + l16;
        #pragma unroll
        for (int kc = 0; kc < 8; ++kc) {
            #pragma unroll
            for (int j = 0; j < 8; ++j)
                w1f[kc][ct][j] = (_Float16)W1[(kc * 32 + quad * 8 + j) * HID + col];
        }
        #pragma unroll
        for (int kc = 0; kc < 4; ++kc) {
            #pragma unroll
            for (int j = 0; j < 8; ++j)
                w2f[kc][ct][j] = (_Float16)W2[(kc * 32 + quad * 8 + j) * HID + col];
        }
        w1c[ct] = W1[256 * HID + col];
        b1f[ct] = b1[col];
        b2f[ct] = b2[col];
    }

    for (int tile = blockIdx.x; tile < nTiles; tile += gridDim.x) {
        __syncthreads();  // protect sA/sH/sDist from previous iteration's readers
        const int ebase = tile * TILE_M;

        // ---- gather src/dst embedding rows (fp16, 16B chunks) ----
        #pragma unroll
        for (int i = 0; i < 4; ++i) {
            int cid  = i * 256 + t;          // 0..1023 chunks of 16B
            int half_ = cid >> 9;            // 0 = src, 1 = dst
            int r    = (cid >> 4) & 31;      // edge row in tile
            int c16  = cid & 15;             // 16B chunk within 256B row
            int e    = ebase + r; if (e >= E) e = E - 1;
            int node = eidx[(size_t)half_ * E + e];
            const uint4* gp = (const uint4*)(nodeEmb + (size_t)node * HID) + c16;
            *(uint4*)(&sA[half_][r][c16 * 8]) = *gp;
        }
        if (t < TILE_M) {
            int e = ebase + t; if (e >= E) e = E - 1;
            int s = eidx[e], d = eidx[(size_t)E + e];
            float dx = pos[3 * (size_t)s]     - pos[3 * (size_t)d];
            float dy = pos[3 * (size_t)s + 1] - pos[3 * (size_t)d + 1];
            float dz = pos[3 * (size_t)s + 2] - pos[3 * (size_t)d + 2];
            sDist[t] = sqrtf(dx * dx + dy * dy + dz * dz);
        }
        __syncthreads();

        // ---- layer 1: acc[rt][ct] = 16x16 tiles of [32 x 128] ----
        floatx4 acc[2][2];
        #pragma unroll
        for (int rt = 0; rt < 2; ++rt)
            #pragma unroll
            for (int ct = 0; ct < 2; ++ct)
                acc[rt][ct] = (floatx4){0.f, 0.f, 0.f, 0.f};
        #pragma unroll
        for (int kc = 0; kc < 8; ++kc) {
            int buf = kc >> 2;                    // k<128 -> src, else dst
            int kin = (kc & 3) * 32 + quad * 8;   // A: k = quad*8 + j
            half8 a0 = *(const half8*)&sA[buf][l16][kin];
            half8 a1 = *(const half8*)&sA[buf][16 + l16][kin];
            acc[0][0] = __builtin_amdgcn_mfma_f32_16x16x32_f16(a0, w1f[kc][0], acc[0][0], 0, 0, 0);
            acc[0][1] = __builtin_amdgcn_mfma_f32_16x16x32_f16(a0, w1f[kc][1], acc[0][1], 0, 0, 0);
            acc[1][0] = __builtin_amdgcn_mfma_f32_16x16x32_f16(a1, w1f[kc][0], acc[1][0], 0, 0, 0);
            acc[1][1] = __builtin_amdgcn_mfma_f32_16x16x32_f16(a1, w1f[kc][1], acc[1][1], 0, 0, 0);
        }
        // epilogue: + dist*w1c + b1, silu, -> sH (C layout: row=quad*4+i, col=l16)
        #pragma unroll
        for (int rt = 0; rt < 2; ++rt)
            #pragma unroll
            for (int ct = 0; ct < 2; ++ct)
                #pragma unroll
                for (int i = 0; i < 4; ++i) {
                    int m   = rt * 16 + quad * 4 + i;
                    int col = colbase + ct * 16 + l16;
                    float v = acc[rt][ct][i] + sDist[m] * w1c[ct] + b1f[ct];
                    v = v / (1.f + __expf(-v));
                    sH[m][col] = (_Float16)v;
                }
        __syncthreads();

        // ---- layer 2 ----
        floatx4 acc2[2][2];
        #pragma unroll
        for (int rt = 0; rt < 2; ++rt)
            #pragma unroll
            for (int ct = 0; ct < 2; ++ct)
                acc2[rt][ct] = (floatx4){0.f, 0.f, 0.f, 0.f};
        #pragma unroll
        for (int kc = 0; kc < 4; ++kc) {
            int kin = kc * 32 + quad * 8;
            half8 a0 = *(const half8*)&sH[l16][kin];
            half8 a1 = *(const half8*)&sH[16 + l16][kin];
            acc2[0][0] = __builtin_amdgcn_mfma_f32_16x16x32_f16(a0, w2f[kc][0], acc2[0][0], 0, 0, 0);
            acc2[0][1] = __builtin_amdgcn_mfma_f32_16x16x32_f16(a0, w2f[kc][1], acc2[0][1], 0, 0, 0);
            acc2[1][0] = __builtin_amdgcn_mfma_f32_16x16x32_f16(a1, w2f[kc][0], acc2[1][0], 0, 0, 0);
            acc2[1][1] = __builtin_amdgcn_mfma_f32_16x16x32_f16(a1, w2f[kc][1], acc2[1][1], 0, 0, 0);
        }
        __syncthreads();  // all sH (H1) reads done before overwrite
        #pragma unroll
        for (int rt = 0; rt < 2; ++rt)
            #pragma unroll
            for (int ct = 0; ct < 2; ++ct)
                #pragma unroll
                for (int i = 0; i < 4; ++i) {
                    int m   = rt * 16 + quad * 4 + i;
                    int col = colbase + ct * 16 + l16;
                    float v = acc2[rt][ct][i] + b2f[ct];
                    v = v / (1.f + __expf(-v));
                    sH[m][col] = (_Float16)v;
                }
        __syncthreads();

        // ---- layer 3: logits[32][4] = H2 @ W3 + b3 (VALU) ----
        {
            int oid = t >> 1;           // 0..127 -> (m, n)
            int kh  = t & 1;            // half of K
            int m = oid >> 2, n = oid & 3;
            const _Float16* hr = &sH[m][0];
            float s = 0.f;
            #pragma unroll 8
            for (int k = kh * 64; k < kh * 64 + 64; ++k)
                s += (float)hr[k] * sW3[k * 4 + n];
            s += __shfl_xor(s, 1, 64);
            if (kh == 0) {
                int e = ebase + m;
                if (e < E) out[(size_t)e * 4 + n] = s + sB3[n];
            }
        }
    }
}

extern "C" void kernel_launch(void* const* d_in, const int* in_sizes, int n_in,
                              void* d_out, int out_size, void* d_ws, size_t ws_size,
                              hipStream_t stream) {
    const float* x   = (const float*)d_in[0];
    const float* pos = (const float*)d_in[1];
    const int*  eidx = (const int*)d_in[2];
    const float* Wa = (const float*)d_in[3];
    const float* ba = (const float*)d_in[4];
    const float* Wp = (const float*)d_in[5];
    const float* bp = (const float*)d_in[6];
    const float* W1 = (const float*)d_in[7];
    const float* b1 = (const float*)d_in[8];
    const float* W2 = (const float*)d_in[9];
    const float* b2 = (const float*)d_in[10];
    const float* W3 = (const float*)d_in[11];
    const float* b3 = (const float*)d_in[12];
    float* out = (float*)d_out;

    int N = in_sizes[0] / 16;   // ATOM_DIM
    int E = in_sizes[2] / 2;

    _Float16* nodeEmb = (_Float16*)d_ws;   // N*128 fp16 = 25.6 MB

    node_emb_kernel<<<2048, 256, 0, stream>>>(x, pos, Wa, ba, Wp, bp, nodeEmb, N);

    int nTiles = (E + TILE_M - 1) / TILE_M;
    edge_mlp_kernel<<<768, 256, 0, stream>>>(nodeEmb, pos, eidx,
                                             W1, b1, W2, b2, W3, b3,
                                             out, E, nTiles);
}